// Round 11
// baseline (34.862 us; speedup 1.0000x reference)
//
#include <hip/hip_runtime.h>

#define F_ALPHA 0.25f
#define F_EPS   1e-8f
#define NB 4   // preds per block

// Force a block-uniform float into an SGPR (compiler can't prove uniformity
// of a VMEM load result; this frees ~44 VGPRs of pred-side state).
__device__ __forceinline__ float rfl(float x) {
    return __builtin_bit_cast(float,
        __builtin_amdgcn_readfirstlane(__builtin_bit_cast(int, x)));
}

// R5 structure + pred state in SGPRs + register cap for 8 waves/SIMD.
__global__ void __launch_bounds__(256, 8)
fused_cost_kernel(const float* __restrict__ logits,      // [N, C]
                  const float4* __restrict__ pred_boxes, // [N]
                  const float4* __restrict__ tgt_boxes,  // [T]
                  const int* __restrict__ tgt_ids,       // [T]
                  float* __restrict__ out,               // [N, T]
                  int N, int C, int T) {
    __shared__ float fcls[NB][96];                       // C <= 96
    const int n0  = blockIdx.x * NB;
    const int tid = threadIdx.x;

    // ---- phase 1: one wave per pred row ----
    {
        const int w = tid >> 6, l = tid & 63;
        const float* lrow = logits + (size_t)(n0 + w) * C;
        for (int c = l; c < C; c += 64) {
            float x = lrow[c];
            float p = 1.0f / (1.0f + expf(-x));
            float om = 1.0f - p;
            float pos = F_ALPHA * om * om * (-logf(p + F_EPS));
            float neg = (1.0f - F_ALPHA) * p * p * (-logf(om + F_EPS));
            fcls[w][c] = 2.0f * (pos - neg) + 2.0f;      // prescaled 2*cls+2
        }
    }

    // pred-side params -> SGPRs via readfirstlane (block-uniform by construction)
    float pcx[NB], pcy[NB], pw_[NB], ph_[NB];
    float px1[NB], py1[NB], px2[NB], py2[NB], parea[NB];
    float* op[NB];
#pragma unroll
    for (int i = 0; i < NB; ++i) {
        const int n = n0 + i;                            // N % NB == 0
        float4 pb = pred_boxes[n];
        pcx[i] = rfl(pb.x); pcy[i] = rfl(pb.y);
        pw_[i] = rfl(pb.z); ph_[i] = rfl(pb.w);
        px1[i] = rfl(pb.x - 0.5f * pb.z);  py1[i] = rfl(pb.y - 0.5f * pb.w);
        px2[i] = rfl(pb.x + 0.5f * pb.z);  py2[i] = rfl(pb.y + 0.5f * pb.w);
        parea[i] = rfl(pb.z * pb.w);
        op[i] = out + (size_t)n * T;                     // SALU (blockIdx-derived)
    }
    __syncthreads();

    auto body = [&](int t) {
        float4 tb = tgt_boxes[t];                        // unit-stride float4
        int id = tgt_ids[t];                             // unit-stride dword
        float clsv[NB] = {fcls[0][id], fcls[1][id], fcls[2][id], fcls[3][id]};
        float tx1 = tb.x - 0.5f * tb.z, ty1 = tb.y - 0.5f * tb.w;
        float tx2 = tb.x + 0.5f * tb.z, ty2 = tb.y + 0.5f * tb.w;
        float tarea = tb.z * tb.w;
#pragma unroll
        for (int i = 0; i < NB; ++i) {
            float l1 = (fabsf(pcx[i] - tb.x) + fabsf(pcy[i] - tb.y))
                     + (fabsf(pw_[i] - tb.z) + fabsf(ph_[i] - tb.w));

            float ix1 = fmaxf(px1[i], tx1), iy1 = fmaxf(py1[i], ty1);
            float ix2 = fminf(px2[i], tx2), iy2 = fminf(py2[i], ty2);
            float iw = fmaxf(ix2 - ix1, 0.0f), ih = fmaxf(iy2 - iy1, 0.0f);
            float inter = iw * ih;
            float uni = parea[i] + tarea - inter;

            float ex1 = fminf(px1[i], tx1), ey1 = fminf(py1[i], ty1);
            float ex2 = fmaxf(px2[i], tx2), ey2 = fmaxf(py2[i], ty2);
            float earea = (ex2 - ex1) * (ey2 - ey1);     // wh >= 0 for [0,1) boxes

            float v = fmaf(5.0f, l1, clsv[i]);           // 5*l1 + 2*cls + 2
            v = fmaf(-2.0f, inter * __builtin_amdgcn_rcpf(uni), v);
            v = fmaf(-2.0f, uni * __builtin_amdgcn_rcpf(earea), v);
            op[i][t] = v;                                // coalesced dword store
        }
    };

    // ---- phase 2: unrolled-by-2 target sweep (R5's best-known loop) ----
    int t = tid;
    for (; t + 256 < T; t += 512) { body(t); body(t + 256); }
    for (; t < T; t += 256) body(t);
}

extern "C" void kernel_launch(void* const* d_in, const int* in_sizes, int n_in,
                              void* d_out, int out_size, void* d_ws, size_t ws_size,
                              hipStream_t stream) {
    const float* logits = (const float*)d_in[0];   // [bs, Q, C]
    const float* pboxes = (const float*)d_in[1];   // [bs, Q, 4]
    const float* tboxes = (const float*)d_in[2];   // [T, 4]
    const int*   tids   = (const int*)d_in[3];     // [T]

    int N = in_sizes[1] / 4;          // bs*Q = 14400
    int C = in_sizes[0] / N;          // 91
    int T = in_sizes[2] / 4;          // 1600

    int grid = N / NB;                // 3600
    fused_cost_kernel<<<grid, 256, 0, stream>>>(
        logits, (const float4*)pboxes, (const float4*)tboxes, tids,
        (float*)d_out, N, C, T);
}